// Round 8
// baseline (157.472 us; speedup 1.0000x reference)
//
#include <hip/hip_runtime.h>
#include <stdint.h>

#define Bn 4096
#define Mn 8192
#define Fn 256
#define HIDn 256
#define Cn 64
#define KY 8            // K-split of M dimension (== #XCDs; one slice per XCD)
#define BM 128          // rows per block (k_main)
#define MCH (Mn / KY)   // 1024 m per block
#define NIT (MCH / 64)  // 16 K-tiles per block
#define LOG2E 1.4426950408889634f

typedef float f32x4 __attribute__((ext_vector_type(4)));
typedef short s16x8 __attribute__((ext_vector_type(8)));

__device__ __forceinline__ uint16_t f2bf(float f) {
    union { float f; uint32_t u; } v; v.f = f;
    uint32_t r = v.u + 0x7FFFu + ((v.u >> 16) & 1u);
    return (uint16_t)(r >> 16);
}
__device__ __forceinline__ float bf2f(uint16_t u) {
    union { uint32_t u; float f; } v; v.u = (uint32_t)u << 16; return v.f;
}

// XOR swizzle for LDS tiles with 128B rows: flips bits 4-6 with row&7 (bits 7-9). Involution.
__device__ __forceinline__ uint32_t swz(uint32_t o) { return o ^ (((o >> 7) & 7u) << 4); }

__device__ __forceinline__ void glds16(const char* g, char* l) {
    __builtin_amdgcn_global_load_lds(
        (const __attribute__((address_space(1))) void*)g,
        (__attribute__((address_space(3))) void*)l, 16, 0, 0);
}

// ---------------------------------------------------------------------------
// Fused prep kernel, role-switched by blockIdx.x:
//  [0, 2048)    : maskpack via ballot -> 4 MB bitmask
//  [2048, 5120) : prep_xy — x[h][b], y[h][m] (PRE-SCALED by log2e), self_bf16
//  [5120, 7168) : tn — neighTg tiled+pre-swizzled bf16 transpose
//  [7168, 8320) : prep_w — enc_wT / out_wT bf16 transposes
__global__ __launch_bounds__(256) void k_prep_all(
    const float* __restrict__ selff, const float* __restrict__ neigh,
    const float* __restrict__ mask, const float* __restrict__ a,
    const float* __restrict__ enc_w, const float* __restrict__ out_w,
    float* __restrict__ x, float* __restrict__ y, uint16_t* __restrict__ self_bf,
    char* __restrict__ neighTg, uint16_t* __restrict__ enc_wT, uint16_t* __restrict__ out_wT,
    uint64_t* __restrict__ bitmask)
{
    __shared__ float tl[32][33];
    const int bid = blockIdx.x;
    if (bid < 2048) {
        const int wid = threadIdx.x >> 6, l = threadIdx.x & 63;
        const size_t base = ((size_t)bid * 4 + wid) * 4096;   // float index
        const float* mp = mask + base + l;
        uint64_t myq = 0;
        #pragma unroll 8
        for (int i = 0; i < 64; ++i) {
            const uint64_t q = __ballot(mp[i * 64] > 0.f);
            if (l == i) myq = q;
        }
        bitmask[base / 64 + l] = myq;
    } else if (bid < 5120) {
        const int w = threadIdx.x >> 6, l = threadIdx.x & 63;
        const int r = (bid - 2048) * 4 + w;           // 0..B+M-1
        const bool is_self = (r < Bn);
        const float* row = is_self ? (selff + (size_t)r * Fn) : (neigh + (size_t)(r - Bn) * Fn);
        const int aoff = is_self ? 0 : Fn;
        const float4 v  = *(const float4*)(row + l * 4);
        const float4 c0 = *(const float4*)(a + aoff + l * 4);
        const float4 c1 = *(const float4*)(a + 2 * Fn + aoff + l * 4);
        float d0 = v.x * c0.x + v.y * c0.y + v.z * c0.z + v.w * c0.w;
        float d1 = v.x * c1.x + v.y * c1.y + v.z * c1.z + v.w * c1.w;
        #pragma unroll
        for (int s = 32; s > 0; s >>= 1) { d0 += __shfl_xor(d0, s); d1 += __shfl_xor(d1, s); }
        if (is_self) {
            uint2 pk;
            pk.x = (uint32_t)f2bf(v.x) | ((uint32_t)f2bf(v.y) << 16);
            pk.y = (uint32_t)f2bf(v.z) | ((uint32_t)f2bf(v.w) << 16);
            *(uint2*)(self_bf + (size_t)r * Fn + l * 4) = pk;
            if (l == 0) { x[r] = d0 * LOG2E; x[Bn + r] = d1 * LOG2E; }
        } else {
            const int m = r - Bn;
            if (l == 0) { y[m] = d0 * LOG2E; y[Mn + m] = d1 * LOG2E; }
        }
    } else if (bid < 7168) {
        const int bid3 = bid - 5120;
        const int tx = threadIdx.x & 31, ty = threadIdx.x >> 5;
        const int m0 = (bid3 & 255) * 32, f0 = (bid3 >> 8) * 32;
        #pragma unroll
        for (int i = 0; i < 4; ++i)
            tl[ty + 8 * i][tx] = neigh[(size_t)(m0 + ty + 8 * i) * Fn + f0 + tx];
        __syncthreads();
        #pragma unroll
        for (int i = 0; i < 4; ++i) {
            const int f = f0 + ty + 8 * i;
            const int m = m0 + tx;
            const uint32_t o = (uint32_t)(f * 128 + (m & 63) * 2);
            *(uint16_t*)(neighTg + (size_t)(m >> 6) * 32768 + swz(o)) = f2bf(tl[tx][ty + 8 * i]);
        }
    } else {
        const int tid = (bid - 7168) * 256 + threadIdx.x;
        if (tid < 2 * HIDn * 512) {
            const int h = tid >> 17;
            const int rr = tid & 131071;
            const int n = rr >> 9, k = rr & 511;
            enc_wT[tid] = f2bf(enc_w[(size_t)h * 512 * HIDn + (size_t)k * HIDn + n]);
        } else {
            const int rr = tid - 2 * HIDn * 512;
            const int n = rr >> 9, k = rr & 511;
            out_wT[rr] = f2bf(out_w[(size_t)k * Cn + n]);
        }
    }
}

// ---------------------------------------------------------------------------
// Main fused kernel (structure unchanged from r7 except exp2).
__global__ __launch_bounds__(512, 2) void k_main(
    const uint8_t* __restrict__ bitb, const float* __restrict__ x, const float* __restrict__ y,
    const char* __restrict__ neighTg, uint16_t* __restrict__ Upart, float* __restrict__ Z4)
{
    __shared__ __align__(16) uint16_t ldsB[2][Fn * 64];       // 2 x 32KB, [f][m] swizzled
    __shared__ __align__(16) uint16_t ldsP[2][2 * BM * 64];   // 2 x 32KB, [h][row][m] swizzled
    __shared__ __align__(16) float ldsY[2 * MCH];             // 8KB (pre-scaled by log2e)
    const int t = threadIdx.x;
    const int w = t >> 6, l = t & 63;
    const int bid = blockIdx.x;
    const int ky = bid & 7;
    const int b0 = (bid >> 3) * BM;
    const int tile0 = ky * NIT;

    const int pb = t >> 2;            // P-build row (0..127), 4 threads/row
    const int pmf = (t & 3) * 16;     // 16 consecutive m's per thread
    const float x0 = x[b0 + pb];
    const float x1 = x[Bn + b0 + pb];
    float z0 = 0.f, z1 = 0.f;

    const int hw = w >> 2;            // head of this wave
    const int n0 = (w & 3) * 64;      // F-column block of this wave

    f32x4 acc[8][4];
    #pragma unroll
    for (int i = 0; i < 8; ++i)
        #pragma unroll
        for (int j = 0; j < 4; ++j)
            acc[i][j] = (f32x4){0.f, 0.f, 0.f, 0.f};

    const uint8_t* bp = bitb + (size_t)(b0 + pb) * (Mn / 8) + ky * (MCH / 8) + (t & 3) * 2;
    const uint32_t po0 = swz((uint32_t)(pb * 128 + (t & 3) * 32));
    const uint32_t po1 = po0 ^ 16u;
    const uint32_t gchunk = (uint32_t)(w * 4096);

    auto stage = [&](int kt, int buf) {
        const char* gb = neighTg + (size_t)(tile0 + kt) * 32768 + gchunk + (uint32_t)(l * 16);
        char* lb = (char*)ldsB[buf] + gchunk;
        #pragma unroll
        for (int c = 0; c < 4; ++c)
            glds16(gb + c * 1024, lb + c * 1024);
    };
    auto buildP = [&](int buf, int kt, uint32_t bits) {
        const float* Y0 = &ldsY[kt * 64 + pmf];
        const float* Y1 = &ldsY[MCH + kt * 64 + pmf];
        f32x4 ya[4], yb[4];
        #pragma unroll
        for (int q = 0; q < 4; ++q) { ya[q] = *(const f32x4*)(Y0 + q * 4); yb[q] = *(const f32x4*)(Y1 + q * 4); }
        uint16_t p0[16], p1[16];
        #pragma unroll
        for (int j = 0; j < 16; ++j) {
            const bool on = (bits >> j) & 1;
            float t0 = x0 + ya[j >> 2][j & 3];
            float s0 = fmaxf(t0, 0.2f * t0);
            float e0 = on ? __builtin_amdgcn_exp2f(s0) : 0.f;
            z0 += e0; p0[j] = f2bf(e0);
            float t1 = x1 + yb[j >> 2][j & 3];
            float s1 = fmaxf(t1, 0.2f * t1);
            float e1 = on ? __builtin_amdgcn_exp2f(s1) : 0.f;
            z1 += e1; p1[j] = f2bf(e1);
        }
        uint4 qa, qb;
        char* pw = (char*)ldsP[buf];
        qa.x = p0[0] | ((uint32_t)p0[1] << 16);  qa.y = p0[2] | ((uint32_t)p0[3] << 16);
        qa.z = p0[4] | ((uint32_t)p0[5] << 16);  qa.w = p0[6] | ((uint32_t)p0[7] << 16);
        qb.x = p0[8] | ((uint32_t)p0[9] << 16);  qb.y = p0[10] | ((uint32_t)p0[11] << 16);
        qb.z = p0[12] | ((uint32_t)p0[13] << 16); qb.w = p0[14] | ((uint32_t)p0[15] << 16);
        *(uint4*)(pw + po0) = qa;
        *(uint4*)(pw + po1) = qb;
        qa.x = p1[0] | ((uint32_t)p1[1] << 16);  qa.y = p1[2] | ((uint32_t)p1[3] << 16);
        qa.z = p1[4] | ((uint32_t)p1[5] << 16);  qa.w = p1[6] | ((uint32_t)p1[7] << 16);
        qb.x = p1[8] | ((uint32_t)p1[9] << 16);  qb.y = p1[10] | ((uint32_t)p1[11] << 16);
        qb.z = p1[12] | ((uint32_t)p1[13] << 16); qb.w = p1[14] | ((uint32_t)p1[15] << 16);
        *(uint4*)(pw + 16384 + po0) = qa;
        *(uint4*)(pw + 16384 + po1) = qb;
    };
    auto mfma_kk = [&](int buf, int kk) {
        const char* pA = (const char*)ldsP[buf] + hw * 16384;
        const char* pB = (const char*)ldsB[buf];
        const uint32_t kb = (uint32_t)((kk * 32 + (l >> 4) * 8) * 2);
        s16x8 af[8], bfr[4];
        #pragma unroll
        for (int i = 0; i < 8; ++i) {
            const uint32_t ar = (uint32_t)(i * 16 + (l & 15));
            af[i] = *(const s16x8*)(pA + swz(ar * 128 + kb));
        }
        #pragma unroll
        for (int j = 0; j < 4; ++j) {
            const uint32_t br = (uint32_t)(n0 + j * 16 + (l & 15));
            bfr[j] = *(const s16x8*)(pB + swz(br * 128 + kb));
        }
        __builtin_amdgcn_s_setprio(1);
        #pragma unroll
        for (int i = 0; i < 8; ++i)
            #pragma unroll
            for (int j = 0; j < 4; ++j)
                acc[i][j] = __builtin_amdgcn_mfma_f32_16x16x32_bf16(af[i], bfr[j], acc[i][j], 0, 0, 0);
        __builtin_amdgcn_s_setprio(0);
    };

    // ---- prologue
    {
        const int lin = t * 4;
        const int h = lin >> 10, mo = lin & 1023;
        *(float4*)&ldsY[lin] = *(const float4*)(y + (size_t)h * Mn + ky * MCH + mo);
    }
    uint32_t b_cur = *(const uint16_t*)(bp);
    uint32_t b_nxt = *(const uint16_t*)(bp + 8);
    stage(0, 0);
    __syncthreads();
    buildP(0, 0, b_cur);
    asm volatile("s_waitcnt lgkmcnt(0)" ::: "memory");
    __builtin_amdgcn_s_barrier();

    // ---- main loop: one barrier per K-tile
    for (int kt = 0; kt < NIT - 1; ++kt) {
        const int cur = kt & 1, nxt = cur ^ 1;
        stage(kt + 1, nxt);
        const int ktf = (kt + 2 < NIT) ? (kt + 2) : (NIT - 1);
        const uint32_t b_fut = *(const uint16_t*)(bp + ktf * 8);
        mfma_kk(cur, 0);
        buildP(nxt, kt + 1, b_nxt);
        mfma_kk(cur, 1);
        b_nxt = b_fut;
        asm volatile("s_waitcnt lgkmcnt(0)" ::: "memory");
        asm volatile("s_waitcnt vmcnt(1)" ::: "memory");
        __builtin_amdgcn_s_barrier();
    }
    mfma_kk((NIT - 1) & 1, 0);
    mfma_kk((NIT - 1) & 1, 1);

    // Z partials
    z0 += __shfl_xor(z0, 1); z0 += __shfl_xor(z0, 2);
    z1 += __shfl_xor(z1, 1); z1 += __shfl_xor(z1, 2);
    if ((t & 3) == 0) {
        Z4[(size_t)(ky * 2 + 0) * Bn + b0 + pb] = z0;
        Z4[(size_t)(ky * 2 + 1) * Bn + b0 + pb] = z1;
    }
    // U partials: bf16 stores
    uint16_t* Up = Upart + ((size_t)(ky * 2 + hw) * Bn + b0) * Fn;
    #pragma unroll
    for (int i = 0; i < 8; ++i)
        #pragma unroll
        for (int j = 0; j < 4; ++j)
            #pragma unroll
            for (int r = 0; r < 4; ++r) {
                const int row = i * 16 + (l >> 4) * 4 + r;
                const int col = n0 + j * 16 + (l & 15);
                Up[(size_t)row * Fn + col] = f2bf(acc[i][j][r]);
            }
}

// ---------------------------------------------------------------------------
// k_enc with FOLDED aggregation: A = [self | sum_ky(Upart)/Z] staged once,
// agg computed on the fly from coalesced 512B-granule Upart reads.
// Grid (128, 2): 32 rows x 256 cols per block, head = blockIdx.y. 2 blocks/CU.
// ldsA rows are 1024B: generalized XOR swizzle byte^((row&7)<<4) both sides.
__global__ __launch_bounds__(512) void k_enc(
    const uint16_t* __restrict__ self_bf, const uint16_t* __restrict__ Upart,
    const float* __restrict__ Z4, const uint16_t* __restrict__ enc_wT,
    uint16_t* __restrict__ enc)
{
    __shared__ __align__(16) char ldsA[32 * 1024];   // 32 rows x 512 k bf16, swizzled
    __shared__ __align__(16) uint16_t ldsW[256 * 64]; // 32KB per K-tile, swizzled
    const int t = threadIdx.x, w = t >> 6, l = t & 63;
    const int b0 = blockIdx.x * 32;
    const int h = blockIdx.y;

    // ---- stage A-full (once): self half (k 0..255) + agg half (k 256..511)
    #pragma unroll
    for (int i = 0; i < 2; ++i) {
        const uint32_t o = (uint32_t)(i * 8192 + t * 16);
        const uint32_t rr = o >> 9, kbyte = o & 511u;
        // self
        const uint4 ds = *(const uint4*)((const char*)self_bf + (size_t)(b0 + rr) * 512 + kbyte);
        *(uint4*)(ldsA + rr * 1024 + (kbyte ^ ((rr & 7u) << 4))) = ds;
        // agg: sum 8 ky partials, scale by 1/Z
        float zs = 0.f;
        #pragma unroll
        for (int ky = 0; ky < KY; ++ky) zs += Z4[(size_t)(ky * 2 + h) * Bn + b0 + rr];
        const float zi = 1.0f / zs;
        float su[8] = {0.f,0.f,0.f,0.f,0.f,0.f,0.f,0.f};
        #pragma unroll
        for (int ky = 0; ky < KY; ++ky) {
            const uint4 raw = *(const uint4*)((const char*)Upart +
                ((size_t)(ky * 2 + h) * Bn + b0 + rr) * 512 + kbyte);
            const uint32_t rw[4] = {raw.x, raw.y, raw.z, raw.w};
            #pragma unroll
            for (int q = 0; q < 4; ++q) {
                su[q * 2 + 0] += bf2f((uint16_t)(rw[q] & 0xFFFFu));
                su[q * 2 + 1] += bf2f((uint16_t)(rw[q] >> 16));
            }
        }
        uint4 pk;
        pk.x = f2bf(su[0] * zi) | ((uint32_t)f2bf(su[1] * zi) << 16);
        pk.y = f2bf(su[2] * zi) | ((uint32_t)f2bf(su[3] * zi) << 16);
        pk.z = f2bf(su[4] * zi) | ((uint32_t)f2bf(su[5] * zi) << 16);
        pk.w = f2bf(su[6] * zi) | ((uint32_t)f2bf(su[7] * zi) << 16);
        *(uint4*)(ldsA + rr * 1024 + ((512u + kbyte) ^ ((rr & 7u) << 4))) = pk;
    }

    const int wrg = (w >> 2) * 16;    // row group
    const int wc = (w & 3) * 64;      // col block
    f32x4 acc[4];
    #pragma unroll
    for (int j = 0; j < 4; ++j) acc[j] = (f32x4){0.f, 0.f, 0.f, 0.f};

    const char* Bsrc = (const char*)(enc_wT + (size_t)h * HIDn * 512);
    __syncthreads();

    for (int kt = 0; kt < 8; ++kt) {
        #pragma unroll
        for (int i = 0; i < 4; ++i) {
            const uint32_t o = (uint32_t)(i * 8192 + t * 16);
            const uint32_t rr = o >> 7, kb = o & 127u;
            const uint4 db = *(const uint4*)(Bsrc + (size_t)rr * 1024 + kt * 128 + kb);
            *(uint4*)((char*)ldsW + swz(o)) = db;
        }
        __syncthreads();
        #pragma unroll
        for (int kk = 0; kk < 2; ++kk) {
            const uint32_t kfb = (uint32_t)(kt * 128 + (kk * 32 + (l >> 4) * 8) * 2);
            const uint32_t ar = (uint32_t)(wrg + (l & 15));
            const s16x8 af = *(const s16x8*)(ldsA + ar * 1024 + (kfb ^ ((ar & 7u) << 4)));
            const uint32_t kb = (uint32_t)((kk * 32 + (l >> 4) * 8) * 2);
            #pragma unroll
            for (int j = 0; j < 4; ++j) {
                const uint32_t br = (uint32_t)(wc + j * 16 + (l & 15));
                const s16x8 bw = *(const s16x8*)((const char*)ldsW + swz(br * 128 + kb));
                acc[j] = __builtin_amdgcn_mfma_f32_16x16x32_bf16(af, bw, acc[j], 0, 0, 0);
            }
        }
        __syncthreads();
    }
    #pragma unroll
    for (int j = 0; j < 4; ++j)
        #pragma unroll
        for (int r = 0; r < 4; ++r) {
            const int row = wrg + (l >> 4) * 4 + r;
            const int col = wc + j * 16 + (l & 15);
            enc[(size_t)(b0 + row) * 512 + h * HIDn + col] = f2bf(fmaxf(acc[j][r], 0.f));
        }
}

// ---------------------------------------------------------------------------
// out[b][c] = enc @ out_w  (f32 out). Grid (64): 64 rows x 64 cols, K=512.
__global__ __launch_bounds__(256) void k_out(
    const uint16_t* __restrict__ enc, const uint16_t* __restrict__ out_wT, float* __restrict__ out)
{
    __shared__ uint16_t ldsA[64 * 64];
    __shared__ uint16_t ldsW[64 * 64];
    const int t = threadIdx.x, w = t >> 6, l = t & 63;
    const int b0 = blockIdx.x * 64;
    const int wr = w * 16;
    f32x4 acc[4];
    #pragma unroll
    for (int j = 0; j < 4; ++j) acc[j] = (f32x4){0.f, 0.f, 0.f, 0.f};

    for (int kt = 0; kt < 8; ++kt) {
        #pragma unroll
        for (int i = 0; i < 2; ++i) {
            const uint32_t o = (uint32_t)(i * 4096 + t * 16);
            const uint32_t rr = o >> 7, kb = o & 127u;
            const uint4 da = *(const uint4*)((const char*)enc + (size_t)(b0 + rr) * 1024 + kt * 128 + kb);
            *(uint4*)((char*)ldsA + swz(o)) = da;
            const uint4 db = *(const uint4*)((const char*)out_wT + (size_t)rr * 1024 + kt * 128 + kb);
            *(uint4*)((char*)ldsW + swz(o)) = db;
        }
        __syncthreads();
        #pragma unroll
        for (int kk = 0; kk < 2; ++kk) {
            const uint32_t kb = (uint32_t)((kk * 32 + (l >> 4) * 8) * 2);
            const uint32_t ar = (uint32_t)(wr + (l & 15));
            const s16x8 af = *(const s16x8*)((const char*)ldsA + swz(ar * 128 + kb));
            #pragma unroll
            for (int j = 0; j < 4; ++j) {
                const uint32_t br = (uint32_t)(j * 16 + (l & 15));
                const s16x8 bw = *(const s16x8*)((const char*)ldsW + swz(br * 128 + kb));
                acc[j] = __builtin_amdgcn_mfma_f32_16x16x32_bf16(af, bw, acc[j], 0, 0, 0);
            }
        }
        __syncthreads();
    }
    #pragma unroll
    for (int j = 0; j < 4; ++j)
        #pragma unroll
        for (int r = 0; r < 4; ++r) {
            const int row = wr + (l >> 4) * 4 + r;
            const int col = j * 16 + (l & 15);
            out[(size_t)(b0 + row) * Cn + col] = acc[j][r];
        }
}

// ---------------------------------------------------------------------------
extern "C" void kernel_launch(void* const* d_in, const int* in_sizes, int n_in,
                              void* d_out, int out_size, void* d_ws, size_t ws_size,
                              hipStream_t stream) {
    const float* self_feats = (const float*)d_in[0];
    const float* neigh      = (const float*)d_in[1];
    const float* mask       = (const float*)d_in[2];
    const float* a          = (const float*)d_in[3];
    const float* enc_w      = (const float*)d_in[4];
    const float* out_w      = (const float*)d_in[5];
    float* out = (float*)d_out;

    char* ws = (char*)d_ws;
    size_t off = 0;
    auto alloc = [&](size_t bytes) { char* p = ws + off; off += (bytes + 255) & ~(size_t)255; return p; };
    uint16_t* Upart   = (uint16_t*)alloc((size_t)KY * 2 * Bn * Fn * 2); // 32 MB bf16
    float*    Z4      = (float*)alloc((size_t)KY * 2 * Bn * 4);         // 256 KB
    float*    x       = (float*)alloc((size_t)2 * Bn * 4);
    float*    y       = (float*)alloc((size_t)2 * Mn * 4);
    char*     neighTg = (char*)alloc((size_t)Fn * Mn * 2);              // 4 MB
    uint16_t* self_bf = (uint16_t*)alloc((size_t)Bn * Fn * 2);          // 2 MB
    uint16_t* enc     = (uint16_t*)alloc((size_t)Bn * 512 * 2);         // 4 MB
    uint16_t* enc_wT  = (uint16_t*)alloc((size_t)2 * HIDn * 512 * 2);
    uint16_t* out_wT  = (uint16_t*)alloc((size_t)Cn * 512 * 2);
    uint64_t* bitmask = (uint64_t*)alloc((size_t)Bn * Mn / 8);          // 4 MB

    k_prep_all<<<8320, 256, 0, stream>>>(self_feats, neigh, mask, a, enc_w, out_w,
                                         x, y, self_bf, neighTg, enc_wT, out_wT, bitmask);
    // PROBE: k_main launched twice (idempotent). dur_us delta vs round 7
    // isolates k_main's true duration; remove next round.
    k_main<<<256, 512, 0, stream>>>((const uint8_t*)bitmask, x, y, neighTg, Upart, Z4);
    k_main<<<256, 512, 0, stream>>>((const uint8_t*)bitmask, x, y, neighTg, Upart, Z4);
    k_enc<<<dim3(128, 2), 512, 0, stream>>>(self_bf, Upart, Z4, enc_wT, enc);
    k_out<<<Bn / 64, 256, 0, stream>>>(enc, out_wT, out);
}

// Round 10
// 141.135 us; speedup vs baseline: 1.1158x; 1.1158x over previous
//
#include <hip/hip_runtime.h>
#include <hip/hip_bf16.h>
#include <stdint.h>

#define Bn 4096
#define Mn 8192
#define Fn 256
#define HIDn 256
#define Cn 64
#define KY 8            // K-split of M dimension (== #XCDs; one slice per XCD)
#define BM 128          // rows per block (k_main)
#define MCH (Mn / KY)   // 1024 m per block
#define NIT (MCH / 64)  // 16 K-tiles per block
#define LOG2E 1.4426950408889634f

typedef float f32x4 __attribute__((ext_vector_type(4)));
typedef short s16x8 __attribute__((ext_vector_type(8)));

__device__ __forceinline__ uint16_t f2bf(float f) {
    union { float f; uint32_t u; } v; v.f = f;
    uint32_t r = v.u + 0x7FFFu + ((v.u >> 16) & 1u);
    return (uint16_t)(r >> 16);
}
__device__ __forceinline__ float bf2f(uint16_t u) {
    union { uint32_t u; float f; } v; v.u = (uint32_t)u << 16; return v.f;
}
// Portable packed f32->bf16x2 (compiles to v_cvt_pk_bf16_f32 on gfx950).
__device__ __forceinline__ uint32_t cvtpk(float a, float b) {
    union { __hip_bfloat162 h; uint32_t u; } v;
    v.h = __float22bfloat162_rn(make_float2(a, b));   // x -> low, y -> high
    return v.u;
}

// XOR swizzle for LDS tiles with 128B rows: flips bits 4-6 with row&7 (bits 7-9). Involution.
__device__ __forceinline__ uint32_t swz(uint32_t o) { return o ^ (((o >> 7) & 7u) << 4); }

__device__ __forceinline__ void glds16(const char* g, char* l) {
    __builtin_amdgcn_global_load_lds(
        (const __attribute__((address_space(1))) void*)g,
        (__attribute__((address_space(3))) void*)l, 16, 0, 0);
}

// ---------------------------------------------------------------------------
// Fused prep kernel, role-switched by blockIdx.x:
//  [0, 2048)    : maskpack via ballot -> 4 MB bitmask
//  [2048, 5120) : prep_xy — x[h][b], y[h][m] (PRE-SCALED by log2e), self_bf16
//  [5120, 7168) : tn — neighTg tiled+pre-swizzled bf16 transpose
//  [7168, 8320) : prep_w — enc_wT (agg-half k-PERMUTED to match k_main's
//                 packed U layout) / out_wT bf16 transposes
__global__ __launch_bounds__(256) void k_prep_all(
    const float* __restrict__ selff, const float* __restrict__ neigh,
    const float* __restrict__ mask, const float* __restrict__ a,
    const float* __restrict__ enc_w, const float* __restrict__ out_w,
    float* __restrict__ x, float* __restrict__ y, uint16_t* __restrict__ self_bf,
    char* __restrict__ neighTg, uint16_t* __restrict__ enc_wT, uint16_t* __restrict__ out_wT,
    uint64_t* __restrict__ bitmask)
{
    __shared__ float tl[32][33];
    const int bid = blockIdx.x;
    if (bid < 2048) {
        const int wid = threadIdx.x >> 6, l = threadIdx.x & 63;
        const size_t base = ((size_t)bid * 4 + wid) * 4096;   // float index
        const float* mp = mask + base + l;
        uint64_t myq = 0;
        #pragma unroll 8
        for (int i = 0; i < 64; ++i) {
            const uint64_t q = __ballot(mp[i * 64] > 0.f);
            if (l == i) myq = q;
        }
        bitmask[base / 64 + l] = myq;
    } else if (bid < 5120) {
        const int w = threadIdx.x >> 6, l = threadIdx.x & 63;
        const int r = (bid - 2048) * 4 + w;           // 0..B+M-1
        const bool is_self = (r < Bn);
        const float* row = is_self ? (selff + (size_t)r * Fn) : (neigh + (size_t)(r - Bn) * Fn);
        const int aoff = is_self ? 0 : Fn;
        const float4 v  = *(const float4*)(row + l * 4);
        const float4 c0 = *(const float4*)(a + aoff + l * 4);
        const float4 c1 = *(const float4*)(a + 2 * Fn + aoff + l * 4);
        float d0 = v.x * c0.x + v.y * c0.y + v.z * c0.z + v.w * c0.w;
        float d1 = v.x * c1.x + v.y * c1.y + v.z * c1.z + v.w * c1.w;
        #pragma unroll
        for (int s = 32; s > 0; s >>= 1) { d0 += __shfl_xor(d0, s); d1 += __shfl_xor(d1, s); }
        if (is_self) {
            uint2 pk;
            pk.x = (uint32_t)f2bf(v.x) | ((uint32_t)f2bf(v.y) << 16);
            pk.y = (uint32_t)f2bf(v.z) | ((uint32_t)f2bf(v.w) << 16);
            *(uint2*)(self_bf + (size_t)r * Fn + l * 4) = pk;
            if (l == 0) { x[r] = d0 * LOG2E; x[Bn + r] = d1 * LOG2E; }
        } else {
            const int m = r - Bn;
            if (l == 0) { y[m] = d0 * LOG2E; y[Mn + m] = d1 * LOG2E; }
        }
    } else if (bid < 7168) {
        const int bid3 = bid - 5120;
        const int tx = threadIdx.x & 31, ty = threadIdx.x >> 5;
        const int m0 = (bid3 & 255) * 32, f0 = (bid3 >> 8) * 32;
        #pragma unroll
        for (int i = 0; i < 4; ++i)
            tl[ty + 8 * i][tx] = neigh[(size_t)(m0 + ty + 8 * i) * Fn + f0 + tx];
        __syncthreads();
        #pragma unroll
        for (int i = 0; i < 4; ++i) {
            const int f = f0 + ty + 8 * i;
            const int m = m0 + tx;
            const uint32_t o = (uint32_t)(f * 128 + (m & 63) * 2);
            *(uint16_t*)(neighTg + (size_t)(m >> 6) * 32768 + swz(o)) = f2bf(tl[tx][ty + 8 * i]);
        }
    } else {
        const int tid = (bid - 7168) * 256 + threadIdx.x;
        if (tid < 2 * HIDn * 512) {
            const int h = tid >> 17;
            const int rr = tid & 131071;
            const int n = rr >> 9, k = rr & 511;
            int kl = k;
            if (k >= 256) {
                // k_main stores agg cols packed: storage e holds logical col
                // perm(e) = (e>>7)*128 + (e&7)*16 + ((e>>3)&15)  (bijective)
                const int e = k - 256;
                kl = 256 + (e >> 7) * 128 + (e & 7) * 16 + ((e >> 3) & 15);
            }
            enc_wT[tid] = f2bf(enc_w[(size_t)h * 512 * HIDn + (size_t)kl * HIDn + n]);
        } else {
            const int rr = tid - 2 * HIDn * 512;
            const int n = rr >> 9, k = rr & 511;
            out_wT[rr] = f2bf(out_w[(size_t)k * Cn + n]);
        }
    }
}

// ---------------------------------------------------------------------------
// Main fused kernel, P-IN-REGISTERS (hardened: __syncthreads everywhere,
// portable bf16 pack). Grid 256 (32 row-blocks x 8 ky, ky=bid&7 XCD-pinned).
// 512 thr = 8 waves: wave = (head hw) x (row-group rg: 64) x (col-group cg: 128).
// Each lane builds its own MFMA A-fragment P-values in VGPRs — no ldsP.
__global__ __launch_bounds__(512) void k_main(
    const uint8_t* __restrict__ bitb, const float* __restrict__ x, const float* __restrict__ y,
    const char* __restrict__ neighTg, uint16_t* __restrict__ Upart, float* __restrict__ Z4)
{
    __shared__ __align__(16) uint16_t ldsB[2][Fn * 64];   // 2 x 32KB, [f][m] swizzled
    __shared__ __align__(16) float ldsY[2 * MCH];         // 8KB (pre-scaled by log2e)
    const int t = threadIdx.x;
    const int w = t >> 6, l = t & 63;
    const int bid = blockIdx.x;
    const int ky = bid & 7;
    const int b0 = (bid >> 3) * BM;
    const int tile0 = ky * NIT;

    const int hw = w >> 2;          // head
    const int rg = (w >> 1) & 1;    // row group (64 rows)
    const int cg = w & 1;           // col group (128 cols)
    const int lr = l & 15;          // row/col-in-tile lane idx
    const int lk = l >> 4;          // k-quarter (0..3)

    f32x4 acc[4][8];
    #pragma unroll
    for (int i = 0; i < 4; ++i)
        #pragma unroll
        for (int j = 0; j < 8; ++j)
            acc[i][j] = (f32x4){0.f, 0.f, 0.f, 0.f};

    // per-lane rows: 4 row-tiles (rt) of 16, row = rg*64 + rt*16 + lr
    float xr[4];
    const uint8_t* bpr[4];
    float zv[4] = {0.f, 0.f, 0.f, 0.f};
    #pragma unroll
    for (int rt = 0; rt < 4; ++rt) {
        const int row = b0 + rg * 64 + rt * 16 + lr;
        xr[rt] = x[(size_t)hw * Bn + row];
        bpr[rt] = bitb + (size_t)row * (Mn / 8) + ky * (MCH / 8);
    }

    const uint32_t gchunk = (uint32_t)(w * 4096);
    auto stage = [&](int kt, int buf) {
        const char* gb = neighTg + (size_t)(tile0 + kt) * 32768 + gchunk + (uint32_t)(l * 16);
        char* lb = (char*)ldsB[buf] + gchunk;
        #pragma unroll
        for (int c = 0; c < 4; ++c)
            glds16(gb + c * 1024, lb + c * 1024);
    };

    auto tile_compute = [&](int kt, int buf, const uint64_t* bitsA) {
        const char* pB = (const char*)ldsB[buf];
        #pragma unroll
        for (int kk = 0; kk < 2; ++kk) {
            const float* Yp = &ldsY[hw * MCH + kt * 64 + kk * 32 + lk * 8];
            const f32x4 ya = *(const f32x4*)Yp;
            const f32x4 yb = *(const f32x4*)(Yp + 4);
            const uint32_t kb = (uint32_t)((kk * 32 + lk * 8) * 2);
            s16x8 bfr[8];
            #pragma unroll
            for (int ct = 0; ct < 8; ++ct) {
                const uint32_t br = (uint32_t)(cg * 128 + ct * 16 + lr);
                bfr[ct] = *(const s16x8*)(pB + swz(br * 128 + kb));
            }
            #pragma unroll
            for (int rt = 0; rt < 4; ++rt) {
                const uint32_t bby = (uint32_t)(bitsA[rt] >> ((kk * 4 + lk) * 8)) & 0xFFu;
                const float x0 = xr[rt];
                float e[8];
                #pragma unroll
                for (int j = 0; j < 8; ++j) {
                    const float yj = (j < 4) ? ya[j] : yb[j - 4];
                    const float tv = x0 + yj;
                    const float s = fmaxf(tv, 0.2f * tv);
                    const float ev = __builtin_amdgcn_exp2f(s);
                    e[j] = ((bby >> j) & 1u) ? ev : 0.f;
                }
                zv[rt] += ((e[0] + e[1]) + (e[2] + e[3])) + ((e[4] + e[5]) + (e[6] + e[7]));
                union { uint32_t u[4]; s16x8 v; } afu;
                afu.u[0] = cvtpk(e[0], e[1]);
                afu.u[1] = cvtpk(e[2], e[3]);
                afu.u[2] = cvtpk(e[4], e[5]);
                afu.u[3] = cvtpk(e[6], e[7]);
                const s16x8 af = afu.v;
                #pragma unroll
                for (int ct = 0; ct < 8; ++ct)
                    acc[rt][ct] = __builtin_amdgcn_mfma_f32_16x16x32_bf16(af, bfr[ct], acc[rt][ct], 0, 0, 0);
            }
        }
    };

    // ---- prologue: ldsY staged; B(0) staged; bits(0) loaded
    {
        const int lin = t * 4;                       // 2048 floats total
        const int h = lin >> 10, mo = lin & 1023;
        *(float4*)&ldsY[lin] = *(const float4*)(y + (size_t)h * Mn + ky * MCH + mo);
    }
    stage(0, 0);
    uint64_t bits[4];
    #pragma unroll
    for (int rt = 0; rt < 4; ++rt) bits[rt] = *(const uint64_t*)(bpr[rt]);
    __syncthreads();                                 // full fence: ldsY + B(0) ready

    // ---- main loop: one __syncthreads per K-tile (full fence, race-proof)
    for (int kt = 0; kt < NIT - 1; ++kt) {
        const int cur = kt & 1, nxt = cur ^ 1;
        stage(kt + 1, nxt);                          // 4 glds -> B[nxt]
        uint64_t nbits[4];
        #pragma unroll
        for (int rt = 0; rt < 4; ++rt) nbits[rt] = *(const uint64_t*)(bpr[rt] + (kt + 1) * 8);
        tile_compute(kt, cur, bits);
        #pragma unroll
        for (int rt = 0; rt < 4; ++rt) bits[rt] = nbits[rt];
        __syncthreads();                             // drains glds + fences LDS
    }
    tile_compute(NIT - 1, (NIT - 1) & 1, bits);

    // ---- Z: reduce across the 4 k-quarter lane groups; cg0 waves store.
    #pragma unroll
    for (int rt = 0; rt < 4; ++rt) {
        zv[rt] += __shfl_xor(zv[rt], 16);
        zv[rt] += __shfl_xor(zv[rt], 32);
    }
    if (cg == 0 && l < 16) {
        #pragma unroll
        for (int rt = 0; rt < 4; ++rt)
            Z4[(size_t)(ky * 2 + hw) * Bn + b0 + rg * 64 + rt * 16 + l] = zv[rt];
    }
    // ---- U: bf16 packed stores (storage e = cg*128 + lr*8 + ct holds logical
    // col cg*128 + ct*16 + lr; compensated by enc_wT permutation in prep).
    uint16_t* Up = Upart + ((size_t)(ky * 2 + hw) * Bn + b0) * Fn;
    #pragma unroll
    for (int rt = 0; rt < 4; ++rt)
        #pragma unroll
        for (int r = 0; r < 4; ++r) {
            const int row = rg * 64 + rt * 16 + lk * 4 + r;
            uint4 pk4;
            pk4.x = cvtpk(acc[rt][0][r], acc[rt][1][r]);
            pk4.y = cvtpk(acc[rt][2][r], acc[rt][3][r]);
            pk4.z = cvtpk(acc[rt][4][r], acc[rt][5][r]);
            pk4.w = cvtpk(acc[rt][6][r], acc[rt][7][r]);
            *(uint4*)((char*)(Up + (size_t)row * Fn) + cg * 256 + lr * 16) = pk4;
        }
}

// ---------------------------------------------------------------------------
// k_enc with FOLDED aggregation: A = [self | sum_ky(Upart)/Z] staged once,
// agg computed on the fly (Upart storage order matches permuted enc_wT).
__global__ __launch_bounds__(512) void k_enc(
    const uint16_t* __restrict__ self_bf, const uint16_t* __restrict__ Upart,
    const float* __restrict__ Z4, const uint16_t* __restrict__ enc_wT,
    uint16_t* __restrict__ enc)
{
    __shared__ __align__(16) char ldsA[32 * 1024];    // 32 rows x 512 k bf16, swizzled
    __shared__ __align__(16) uint16_t ldsW[256 * 64]; // 32KB per K-tile, swizzled
    const int t = threadIdx.x, w = t >> 6, l = t & 63;
    const int b0 = blockIdx.x * 32;
    const int h = blockIdx.y;

    #pragma unroll
    for (int i = 0; i < 2; ++i) {
        const uint32_t o = (uint32_t)(i * 8192 + t * 16);
        const uint32_t rr = o >> 9, kbyte = o & 511u;
        const uint4 ds = *(const uint4*)((const char*)self_bf + (size_t)(b0 + rr) * 512 + kbyte);
        *(uint4*)(ldsA + rr * 1024 + (kbyte ^ ((rr & 7u) << 4))) = ds;
        float zs = 0.f;
        #pragma unroll
        for (int ky = 0; ky < KY; ++ky) zs += Z4[(size_t)(ky * 2 + h) * Bn + b0 + rr];
        const float zi = 1.0f / fmaxf(zs, 1e-35f);    // guard: finite diagnostics, no 0*inf
        float su[8] = {0.f,0.f,0.f,0.f,0.f,0.f,0.f,0.f};
        #pragma unroll
        for (int ky = 0; ky < KY; ++ky) {
            const uint4 raw = *(const uint4*)((const char*)Upart +
                ((size_t)(ky * 2 + h) * Bn + b0 + rr) * 512 + kbyte);
            const uint32_t rw[4] = {raw.x, raw.y, raw.z, raw.w};
            #pragma unroll
            for (int q = 0; q < 4; ++q) {
                su[q * 2 + 0] += bf2f((uint16_t)(rw[q] & 0xFFFFu));
                su[q * 2 + 1] += bf2f((uint16_t)(rw[q] >> 16));
            }
        }
        uint4 pk;
        pk.x = f2bf(su[0] * zi) | ((uint32_t)f2bf(su[1] * zi) << 16);
        pk.y = f2bf(su[2] * zi) | ((uint32_t)f2bf(su[3] * zi) << 16);
        pk.z = f2bf(su[4] * zi) | ((uint32_t)f2bf(su[5] * zi) << 16);
        pk.w = f2bf(su[6] * zi) | ((uint32_t)f2bf(su[7] * zi) << 16);
        *(uint4*)(ldsA + rr * 1024 + ((512u + kbyte) ^ ((rr & 7u) << 4))) = pk;
    }

    const int wrg = (w >> 2) * 16;
    const int wc = (w & 3) * 64;
    f32x4 acc[4];
    #pragma unroll
    for (int j = 0; j < 4; ++j) acc[j] = (f32x4){0.f, 0.f, 0.f, 0.f};

    const char* Bsrc = (const char*)(enc_wT + (size_t)h * HIDn * 512);
    __syncthreads();

    for (int kt = 0; kt < 8; ++kt) {
        #pragma unroll
        for (int i = 0; i < 4; ++i) {
            const uint32_t o = (uint32_t)(i * 8192 + t * 16);
            const uint32_t rr = o >> 7, kb = o & 127u;
            const uint4 db = *(const uint4*)(Bsrc + (size_t)rr * 1024 + kt * 128 + kb);
            *(uint4*)((char*)ldsW + swz(o)) = db;
        }
        __syncthreads();
        #pragma unroll
        for (int kk = 0; kk < 2; ++kk) {
            const uint32_t kfb = (uint32_t)(kt * 128 + (kk * 32 + (l >> 4) * 8) * 2);
            const uint32_t ar = (uint32_t)(wrg + (l & 15));
            const s16x8 af = *(const s16x8*)(ldsA + ar * 1024 + (kfb ^ ((ar & 7u) << 4)));
            const uint32_t kb = (uint32_t)((kk * 32 + (l >> 4) * 8) * 2);
            #pragma unroll
            for (int j = 0; j < 4; ++j) {
                const uint32_t br = (uint32_t)(wc + j * 16 + (l & 15));
                const s16x8 bw = *(const s16x8*)((const char*)ldsW + swz(br * 128 + kb));
                acc[j] = __builtin_amdgcn_mfma_f32_16x16x32_bf16(af, bw, acc[j], 0, 0, 0);
            }
        }
        __syncthreads();
    }
    #pragma unroll
    for (int j = 0; j < 4; ++j)
        #pragma unroll
        for (int r = 0; r < 4; ++r) {
            const int row = wrg + (l >> 4) * 4 + r;
            const int col = wc + j * 16 + (l & 15);
            enc[(size_t)(b0 + row) * 512 + h * HIDn + col] = f2bf(fmaxf(acc[j][r], 0.f));
        }
}

// ---------------------------------------------------------------------------
// out[b][c] = enc @ out_w  (f32 out). Grid (64): 64 rows x 64 cols, K=512.
__global__ __launch_bounds__(256) void k_out(
    const uint16_t* __restrict__ enc, const uint16_t* __restrict__ out_wT, float* __restrict__ out)
{
    __shared__ uint16_t ldsA[64 * 64];
    __shared__ uint16_t ldsW[64 * 64];
    const int t = threadIdx.x, w = t >> 6, l = t & 63;
    const int b0 = blockIdx.x * 64;
    const int wr = w * 16;
    f32x4 acc[4];
    #pragma unroll
    for (int j = 0; j < 4; ++j) acc[j] = (f32x4){0.f, 0.f, 0.f, 0.f};

    for (int kt = 0; kt < 8; ++kt) {
        #pragma unroll
        for (int i = 0; i < 2; ++i) {
            const uint32_t o = (uint32_t)(i * 4096 + t * 16);
            const uint32_t rr = o >> 7, kb = o & 127u;
            const uint4 da = *(const uint4*)((const char*)enc + (size_t)(b0 + rr) * 1024 + kt * 128 + kb);
            *(uint4*)((char*)ldsA + swz(o)) = da;
            const uint4 db = *(const uint4*)((const char*)out_wT + (size_t)rr * 1024 + kt * 128 + kb);
            *(uint4*)((char*)ldsW + swz(o)) = db;
        }
        __syncthreads();
        #pragma unroll
        for (int kk = 0; kk < 2; ++kk) {
            const uint32_t kb = (uint32_t)((kk * 32 + (l >> 4) * 8) * 2);
            const uint32_t ar = (uint32_t)(wr + (l & 15));
            const s16x8 af = *(const s16x8*)((const char*)ldsA + swz(ar * 128 + kb));
            #pragma unroll
            for (int j = 0; j < 4; ++j) {
                const uint32_t br = (uint32_t)(j * 16 + (l & 15));
                const s16x8 bw = *(const s16x8*)((const char*)ldsW + swz(br * 128 + kb));
                acc[j] = __builtin_amdgcn_mfma_f32_16x16x32_bf16(af, bw, acc[j], 0, 0, 0);
            }
        }
        __syncthreads();
    }
    #pragma unroll
    for (int j = 0; j < 4; ++j)
        #pragma unroll
        for (int r = 0; r < 4; ++r) {
            const int row = wr + (l >> 4) * 4 + r;
            const int col = j * 16 + (l & 15);
            out[(size_t)(b0 + row) * Cn + col] = acc[j][r];
        }
}

// ---------------------------------------------------------------------------
extern "C" void kernel_launch(void* const* d_in, const int* in_sizes, int n_in,
                              void* d_out, int out_size, void* d_ws, size_t ws_size,
                              hipStream_t stream) {
    const float* self_feats = (const float*)d_in[0];
    const float* neigh      = (const float*)d_in[1];
    const float* mask       = (const float*)d_in[2];
    const float* a          = (const float*)d_in[3];
    const float* enc_w      = (const float*)d_in[4];
    const float* out_w      = (const float*)d_in[5];
    float* out = (float*)d_out;

    char* ws = (char*)d_ws;
    size_t off = 0;
    auto alloc = [&](size_t bytes) { char* p = ws + off; off += (bytes + 255) & ~(size_t)255; return p; };
    uint16_t* Upart   = (uint16_t*)alloc((size_t)KY * 2 * Bn * Fn * 2); // 32 MB bf16
    float*    Z4      = (float*)alloc((size_t)KY * 2 * Bn * 4);         // 256 KB
    float*    x       = (float*)alloc((size_t)2 * Bn * 4);
    float*    y       = (float*)alloc((size_t)2 * Mn * 4);
    char*     neighTg = (char*)alloc((size_t)Fn * Mn * 2);              // 4 MB
    uint16_t* self_bf = (uint16_t*)alloc((size_t)Bn * Fn * 2);          // 2 MB
    uint16_t* enc     = (uint16_t*)alloc((size_t)Bn * 512 * 2);         // 4 MB
    uint16_t* enc_wT  = (uint16_t*)alloc((size_t)2 * HIDn * 512 * 2);
    uint16_t* out_wT  = (uint16_t*)alloc((size_t)Cn * 512 * 2);
    uint64_t* bitmask = (uint64_t*)alloc((size_t)Bn * Mn / 8);          // 4 MB

    k_prep_all<<<8320, 256, 0, stream>>>(self_feats, neigh, mask, a, enc_w, out_w,
                                         x, y, self_bf, neighTg, enc_wT, out_wT, bitmask);
    k_main<<<256, 512, 0, stream>>>((const uint8_t*)bitmask, x, y, neighTg, Upart, Z4);
    k_enc<<<dim3(128, 2), 512, 0, stream>>>(self_bf, Upart, Z4, enc_wT, enc);
    k_out<<<Bn / 64, 256, 0, stream>>>(enc, out_wT, out);
}